// Round 4
// baseline (850.007 us; speedup 1.0000x reference)
//
#include <hip/hip_runtime.h>

#define B_    32768
#define IN_   512
#define HID_  256
#define OUT_  128
#define E_    16
#define CTX_  256
#define DEMO_ 16
#define GIN_  784

typedef __attribute__((ext_vector_type(8))) short short8;   // 8 bf16 = 4 VGPRs
typedef __attribute__((ext_vector_type(4))) float floatx4;  // MFMA C/D

// fp32 -> bf16 round-to-nearest-even
__device__ __forceinline__ short f2bf(float x){
  unsigned u = __builtin_bit_cast(unsigned, x);
  u += 0x7FFFu + ((u >> 16) & 1u);
  return (short)(u >> 16);
}

__device__ __forceinline__ short8 pack8(float4 a, float4 b){
  short8 r;
  r[0]=f2bf(a.x); r[1]=f2bf(a.y); r[2]=f2bf(a.z); r[3]=f2bf(a.w);
  r[4]=f2bf(b.x); r[5]=f2bf(b.y); r[6]=f2bf(b.z); r[7]=f2bf(b.w);
  return r;
}

__device__ __forceinline__ void load_lds16(const short* g, short* l){
  __builtin_amdgcn_global_load_lds((const __attribute__((address_space(1))) void*)g,
                                   (__attribute__((address_space(3))) void*)l,
                                   16, 0, 0);
}

// ---------------- fp32 -> bf16 convert (x, W1, W2) ----------------
__global__ void convert_kernel(const float* __restrict__ x, const float* __restrict__ w1,
                               const float* __restrict__ w2, short* __restrict__ xb,
                               short* __restrict__ w1b, short* __restrict__ w2b){
  const int N1 = B_*IN_, N2 = E_*HID_*IN_, N3 = E_*OUT_*HID_;
  const int total4 = (N1 + N2 + N3) >> 2;
  for (int i = blockIdx.x*blockDim.x + threadIdx.x; i < total4; i += gridDim.x*blockDim.x){
    int e4 = i << 2;
    const float* src; short* dst; int off;
    if (e4 < N1)            { src = x;  dst = xb;  off = e4; }
    else if (e4 < N1 + N2)  { src = w1; dst = w1b; off = e4 - N1; }
    else                    { src = w2; dst = w2b; off = e4 - (N1 + N2); }
    float4 v = *(const float4*)(src + off);
    *(short4*)(dst + off) = make_short4(f2bf(v.x), f2bf(v.y), f2bf(v.z), f2bf(v.w));
  }
}

// ---------------- fused gate + MoE, barrier-free expert loop ----------------
// Block: 512 threads (8 waves), 64 batch rows. x[64][512] bf16 resident in LDS.
// Wave (m_g = wv&1, h_g = wv>>2? no: wv>>1) owns M32 x H64. W1/W2 stream from
// global into registers (L2-resident, no barriers -> compiler-pipelined vmcnt).
// GEMM2 is K-split per wave over its own h64; cross-wave reduce at the end.
__global__ __launch_bounds__(512, 2)
void moe_kernel(const short* __restrict__ xb, const short* __restrict__ w1b,
                const short* __restrict__ w2b,
                const float* __restrict__ u, const float* __restrict__ dd,
                const float* __restrict__ gWf, const float* __restrict__ gbf,
                const float* __restrict__ b1g, const float* __restrict__ b2g,
                float* __restrict__ out){
  __shared__ alignas(16) short s_x[64*512];   // 65536 B (reused: gate tmp, x tile, reduction)

  const int tid  = threadIdx.x;
  const int wv   = tid >> 6;
  const int lane = tid & 63;
  const int l15  = lane & 15;
  const int hi2  = lane >> 4;
  const int m_g  = wv & 1;        // m 32-group
  const int h_g  = wv >> 1;       // h 64-group (0..3)
  const int blk_m0 = blockIdx.x * 64;

  float* sg = (float*)s_x;        // gate weights [64][17] fp32 (temporary)

  // ============ phase 0: gate logits+softmax (waves 0..3, one m16-group each) ============
  if (wv < 4){
    const int mrow = blk_m0 + wv*16 + l15;      // B-operand col (batch row)
    floatx4 ga = {0.f,0.f,0.f,0.f};
    #pragma unroll
    for (int t = 0; t < 8; ++t){                // u segment k=0..255
      const int k = t*32 + hi2*8;
      short8 bfr = pack8(*(const float4*)&u[(size_t)mrow*CTX_ + k],
                         *(const float4*)&u[(size_t)mrow*CTX_ + k + 4]);
      short8 afr = pack8(*(const float4*)&gWf[(size_t)l15*GIN_ + k],
                         *(const float4*)&gWf[(size_t)l15*GIN_ + k + 4]);
      ga = __builtin_amdgcn_mfma_f32_16x16x32_bf16(afr, bfr, ga, 0,0,0);
    }
    #pragma unroll
    for (int t = 0; t < 16; ++t){               // x segment k=256..767 (bf16 pre-converted)
      const int k = t*32 + hi2*8;
      short8 bfr = *(const short8*)&xb[(size_t)mrow*IN_ + k];
      short8 afr = pack8(*(const float4*)&gWf[(size_t)l15*GIN_ + 256 + k],
                         *(const float4*)&gWf[(size_t)l15*GIN_ + 256 + k + 4]);
      ga = __builtin_amdgcn_mfma_f32_16x16x32_bf16(afr, bfr, ga, 0,0,0);
    }
    {                                           // d segment k=768..783, zero-pad to 32
      short8 afr = {0,0,0,0,0,0,0,0}, bfr = {0,0,0,0,0,0,0,0};
      if (hi2 < 2){
        bfr = pack8(*(const float4*)&dd[(size_t)mrow*DEMO_ + hi2*8],
                    *(const float4*)&dd[(size_t)mrow*DEMO_ + hi2*8 + 4]);
        afr = pack8(*(const float4*)&gWf[(size_t)l15*GIN_ + 768 + hi2*8],
                    *(const float4*)&gWf[(size_t)l15*GIN_ + 768 + hi2*8 + 4]);
      }
      ga = __builtin_amdgcn_mfma_f32_16x16x32_bf16(afr, bfr, ga, 0,0,0);
    }
    // lane holds logits for m=l15 (col), e=hi2*4+r (row). softmax over e.
    float v[4];
    #pragma unroll
    for (int r = 0; r < 4; ++r) v[r] = ga[r] + gbf[hi2*4 + r];
    float mx = fmaxf(fmaxf(v[0],v[1]), fmaxf(v[2],v[3]));
    mx = fmaxf(mx, __shfl_xor(mx, 16));
    mx = fmaxf(mx, __shfl_xor(mx, 32));
    float p[4], s = 0.f;
    #pragma unroll
    for (int r = 0; r < 4; ++r){ p[r] = __expf(v[r]-mx); s += p[r]; }
    s += __shfl_xor(s, 16);
    s += __shfl_xor(s, 32);
    const float inv = 1.f / s;
    #pragma unroll
    for (int r = 0; r < 4; ++r) sg[(wv*16 + l15)*17 + hi2*4 + r] = p[r]*inv;
  }
  __syncthreads();

  // ---- oacc init: h_g==0 waves seed with the b2 mixture term, others zero ----
  floatx4 oacc[2][8];
  #pragma unroll
  for (int mt = 0; mt < 2; ++mt)
    #pragma unroll
    for (int ot = 0; ot < 8; ++ot) oacc[mt][ot] = floatx4{0.f,0.f,0.f,0.f};
  if (h_g == 0){
    #pragma unroll 1
    for (int e = 0; e < E_; ++e){
      float b2v[8];
      #pragma unroll
      for (int ot = 0; ot < 8; ++ot) b2v[ot] = b2g[e*OUT_ + ot*16 + l15];
      #pragma unroll
      for (int mt = 0; mt < 2; ++mt)
        #pragma unroll
        for (int r = 0; r < 4; ++r){
          const float wg = sg[(m_g*32 + mt*16 + hi2*4 + r)*17 + e];
          #pragma unroll
          for (int ot = 0; ot < 8; ++ot) oacc[mt][ot][r] += wg*b2v[ot];
        }
    }
  }
  // every lane: gate weights for its GEMM2-A rows (m = m_g*32 + mt*16 + l15)
  float w_my[2][16];
  #pragma unroll
  for (int mt = 0; mt < 2; ++mt)
    #pragma unroll
    for (int e = 0; e < E_; ++e)
      w_my[mt][e] = sg[(m_g*32 + mt*16 + l15)*17 + e];
  __syncthreads();

  // ============ phase 1: stage x[64][512] into LDS (XOR-swizzled 16B blocks) ============
  #pragma unroll
  for (int i = 0; i < 8; ++i){
    const int row = wv + i*8;                      // wave-uniform
    const int cb  = (lane & 56) | ((lane ^ row) & 7);
    load_lds16(&xb[(size_t)(blk_m0 + row)*IN_ + cb*8], s_x + row*512);
  }
  __syncthreads();

  // ============ phase 2: 16 experts, no barriers in the hot loop ============
  #pragma unroll 1
  for (int e = 0; e < E_; ++e){
    // ---- GEMM1: g1[mt][ht] = W1[h64] @ x^T (+b1 via C-init) ----
    floatx4 g1[2][4];
    #pragma unroll
    for (int ht = 0; ht < 4; ++ht){
      const float4 bv = *(const float4*)&b1g[e*HID_ + h_g*64 + ht*16 + hi2*4];
      g1[0][ht] = floatx4{bv.x, bv.y, bv.z, bv.w};
      g1[1][ht] = g1[0][ht];
    }
    const short* w1e = w1b + ((size_t)e*HID_ + h_g*64) * IN_;
    #pragma unroll
    for (int ks = 0; ks < 16; ++ks){
      short8 af[4], bf[2];
      #pragma unroll
      for (int ht = 0; ht < 4; ++ht)
        af[ht] = *(const short8*)&w1e[(size_t)(ht*16 + l15)*IN_ + ks*32 + hi2*8];
      #pragma unroll
      for (int mt = 0; mt < 2; ++mt){
        const int m   = m_g*32 + mt*16 + l15;
        const int cbl = ks*4 + hi2;
        const int phys = (cbl & ~7) | ((cbl ^ m) & 7);
        bf[mt] = *(const short8*)&s_x[m*512 + phys*8];
      }
      #pragma unroll
      for (int mt = 0; mt < 2; ++mt)
        #pragma unroll
        for (int ht = 0; ht < 4; ++ht)
          g1[mt][ht] = __builtin_amdgcn_mfma_f32_16x16x32_bf16(af[ht], bf[mt], g1[mt][ht], 0,0,0);
    }

    // ---- epilogue in-register: relu * gate -> bf16, k-permuted A-frags ----
    // a2[ks][mt] position (hi2,j): h = ks*32 + 16*(j>=4) + hi2*4 + (j&3)
    short8 a2[2][2];
    #pragma unroll
    for (int mt = 0; mt < 2; ++mt){
      const float wg = w_my[mt][e];
      short pk[16];
      #pragma unroll
      for (int ht = 0; ht < 4; ++ht)
        #pragma unroll
        for (int r = 0; r < 4; ++r)
          pk[ht*4 + r] = f2bf(fmaxf(g1[mt][ht][r], 0.f) * wg);
      #pragma unroll
      for (int ks = 0; ks < 2; ++ks)
        #pragma unroll
        for (int j = 0; j < 8; ++j)
          a2[ks][mt][j] = pk[ks*8 + j];
    }

    // ---- GEMM2 (K-split = this wave's h64): oacc += H_slice @ W2^T ----
    const short* w2e = w2b + (size_t)e*OUT_*HID_ + h_g*64;
    #pragma unroll
    for (int ot = 0; ot < 8; ++ot){
      #pragma unroll
      for (int ks = 0; ks < 2; ++ks){
        const short* p = &w2e[(size_t)(ot*16 + l15)*HID_ + ks*32 + hi2*4];
        const short4 lo = *(const short4*)p;
        const short4 hi = *(const short4*)(p + 16);
        short8 bfr;
        bfr[0]=lo.x; bfr[1]=lo.y; bfr[2]=lo.z; bfr[3]=lo.w;
        bfr[4]=hi.x; bfr[5]=hi.y; bfr[6]=hi.z; bfr[7]=hi.w;
        #pragma unroll
        for (int mt = 0; mt < 2; ++mt)
          oacc[mt][ot] = __builtin_amdgcn_mfma_f32_16x16x32_bf16(a2[ks][mt], bfr, oacc[mt][ot], 0,0,0);
      }
    }
    __builtin_amdgcn_s_barrier();   // lockstep waves for L1 reuse; no LDS hazard here
  }

  // ============ phase 3: cross-wave K-reduction through LDS, direct stores ============
  __syncthreads();                  // all x-LDS reads done; s_x reusable
  float* red = (float*)s_x;         // 4 slices x [32m][128o] fp32 = 64 KB
  if (h_g >= 2){
    const int s = (h_g - 2)*2 + m_g;
    #pragma unroll
    for (int mt = 0; mt < 2; ++mt)
      #pragma unroll
      for (int ot = 0; ot < 8; ++ot)
        #pragma unroll
        for (int r = 0; r < 4; ++r)
          red[s*4096 + (mt*16 + hi2*4 + r)*128 + ot*16 + l15] = oacc[mt][ot][r];
  }
  __syncthreads();
  if (h_g < 2){
    const int s = h_g*2 + m_g;
    #pragma unroll
    for (int mt = 0; mt < 2; ++mt)
      #pragma unroll
      for (int ot = 0; ot < 8; ++ot)
        #pragma unroll
        for (int r = 0; r < 4; ++r)
          oacc[mt][ot][r] += red[s*4096 + (mt*16 + hi2*4 + r)*128 + ot*16 + l15];
  }
  __syncthreads();
  if (h_g == 1){
    #pragma unroll
    for (int mt = 0; mt < 2; ++mt)
      #pragma unroll
      for (int ot = 0; ot < 8; ++ot)
        #pragma unroll
        for (int r = 0; r < 4; ++r)
          red[m_g*4096 + (mt*16 + hi2*4 + r)*128 + ot*16 + l15] = oacc[mt][ot][r];
  }
  __syncthreads();
  if (h_g == 0){
    #pragma unroll
    for (int mt = 0; mt < 2; ++mt)
      #pragma unroll
      for (int ot = 0; ot < 8; ++ot)
        #pragma unroll
        for (int r = 0; r < 4; ++r){
          const float v = oacc[mt][ot][r] + red[m_g*4096 + (mt*16 + hi2*4 + r)*128 + ot*16 + l15];
          out[(size_t)(blk_m0 + m_g*32 + mt*16 + hi2*4 + r)*OUT_ + ot*16 + l15] = v;
        }
  }
}

extern "C" void kernel_launch(void* const* d_in, const int* in_sizes, int n_in,
                              void* d_out, int out_size, void* d_ws, size_t ws_size,
                              hipStream_t stream){
  const float* x  = (const float*)d_in[0];
  const float* u  = (const float*)d_in[1];
  const float* dd = (const float*)d_in[2];
  const float* gW = (const float*)d_in[3];
  const float* gb = (const float*)d_in[4];
  const float* W1 = (const float*)d_in[5];
  const float* b1 = (const float*)d_in[6];
  const float* W2 = (const float*)d_in[7];
  const float* b2 = (const float*)d_in[8];
  float* out = (float*)d_out;

  short* xb  = (short*)d_ws;
  short* w1b = xb  + (size_t)B_*IN_;
  short* w2b = w1b + (size_t)E_*HID_*IN_;

  hipLaunchKernelGGL(convert_kernel, dim3(4096), dim3(256), 0, stream, x, W1, W2, xb, w1b, w2b);
  hipLaunchKernelGGL(moe_kernel, dim3(B_/64), dim3(512), 0, stream,
                     xb, w1b, w2b, u, dd, gW, gb, b1, b2, out);
  (void)in_sizes; (void)n_in; (void)out_size; (void)ws_size;
}

// Round 5
// 421.690 us; speedup vs baseline: 2.0157x; 2.0157x over previous
//
#include <hip/hip_runtime.h>

#define B_    32768
#define IN_   512
#define HID_  256
#define OUT_  128
#define E_    16
#define CTX_  256
#define DEMO_ 16
#define GIN_  784

typedef __attribute__((ext_vector_type(8))) short short8;   // 8 bf16 = 4 VGPRs
typedef __attribute__((ext_vector_type(4))) float floatx4;  // MFMA C/D

// fp32 -> bf16 round-to-nearest-even
__device__ __forceinline__ short f2bf(float x){
  unsigned u = __builtin_bit_cast(unsigned, x);
  u += 0x7FFFu + ((u >> 16) & 1u);
  return (short)(u >> 16);
}

__device__ __forceinline__ short8 pack8(float4 a, float4 b){
  short8 r;
  r[0]=f2bf(a.x); r[1]=f2bf(a.y); r[2]=f2bf(a.z); r[3]=f2bf(a.w);
  r[4]=f2bf(b.x); r[5]=f2bf(b.y); r[6]=f2bf(b.z); r[7]=f2bf(b.w);
  return r;
}

__device__ __forceinline__ void load_lds16(const short* g, short* l){
  __builtin_amdgcn_global_load_lds((const __attribute__((address_space(1))) void*)g,
                                   (__attribute__((address_space(3))) void*)l,
                                   16, 0, 0);
}

// Stage a [ROWS][64]-short tile global->LDS, 512 threads, XOR-swizzle on 16B blocks:
// LDS[row][cb] holds G[row][cb ^ (row&7)]; reader uses phys = logical ^ (row&7).
template<int ROWS>
__device__ __forceinline__ void stage_rows64(short* lds, const short* g, int gpitch, int tid){
  const int wvv = tid >> 6, ln = tid & 63;
  const int cb = ln & 7, rsub = ln >> 3;
  #pragma unroll
  for (int p = 0; p < ROWS/64; ++p){
    const int r0  = p*64 + wvv*8;            // wave-uniform row base
    const int row = r0 + rsub;
    load_lds16(g + (size_t)row*gpitch + ((cb ^ rsub) << 3), lds + r0*64);
  }
}

// ---------------- fp32 -> bf16 convert (x, W1, W2) ----------------
__global__ void convert_kernel(const float* __restrict__ x, const float* __restrict__ w1,
                               const float* __restrict__ w2, short* __restrict__ xb,
                               short* __restrict__ w1b, short* __restrict__ w2b){
  const int N1 = B_*IN_, N2 = E_*HID_*IN_, N3 = E_*OUT_*HID_;
  const int total4 = (N1 + N2 + N3) >> 2;
  for (int i = blockIdx.x*blockDim.x + threadIdx.x; i < total4; i += gridDim.x*blockDim.x){
    int e4 = i << 2;
    const float* src; short* dst; int off;
    if (e4 < N1)            { src = x;  dst = xb;  off = e4; }
    else if (e4 < N1 + N2)  { src = w1; dst = w1b; off = e4 - N1; }
    else                    { src = w2; dst = w2b; off = e4 - (N1 + N2); }
    float4 v = *(const float4*)(src + off);
    *(short4*)(dst + off) = make_short4(f2bf(v.x), f2bf(v.y), f2bf(v.z), f2bf(v.w));
  }
}

// ---------------- fused gate + MoE ----------------
// Grid 256 (1 block/CU), 512 threads (8 waves: m_g = wv&1 over 64 m-rows,
// s = wv>>1 over h-quarters(GEMM1)/o-groups(GEMM2)). Block: 128 m x 16 experts
// x full HID. Staging always via global_load_lds; H in-register (k-perm trick)
// for own quarter, quarter-sized LDS exchange for the rest. No atomics.
__global__ __launch_bounds__(512, 2)
void moe_kernel(const short* __restrict__ xb, const short* __restrict__ w1b,
                const short* __restrict__ w2b,
                const float* __restrict__ u, const float* __restrict__ dd,
                const float* __restrict__ gWf, const float* __restrict__ gbf,
                const float* __restrict__ b1g, const float* __restrict__ b2g,
                float* __restrict__ out){
  __shared__ alignas(16) char smem[57856];
  short* s_x  = (short*)smem;             // [128][64] x kc-chunk (GEMM1)
  short* s_w1 = (short*)(smem + 16384);   // [256][64] W1_e kc-chunk (GEMM1)
  short* s_h  = (short*)smem;             // [128][64] H quarter (GEMM2), aliases s_x
  short* s_w2 = (short*)(smem + 16384);   // [128][64] W2 quarter (GEMM2), aliases s_w1
  float* sg   = (float*)(smem + 49152);   // [128][17] gate weights, alive all kernel

  const int tid  = threadIdx.x;
  const int wv   = tid >> 6;
  const int lane = tid & 63;
  const int l15  = lane & 15;
  const int hi2  = lane >> 4;
  const int m_g  = wv & 1;        // 64-row m-group
  const int s    = wv >> 1;       // h-quarter (GEMM1) / o-group (GEMM2), 0..3
  const int blk_m0 = blockIdx.x * 128;

  // ======== phase 0: gate softmax(cat(u,x,d)@gW^T + gb), one m16-group/wave ========
  {
    const int mrow = blk_m0 + wv*16 + l15;       // B-operand col (batch row)
    floatx4 ga = {0.f,0.f,0.f,0.f};
    #pragma unroll
    for (int t = 0; t < 8; ++t){                 // u segment k=0..255
      const int k = t*32 + hi2*8;
      short8 bfr = pack8(*(const float4*)&u[(size_t)mrow*CTX_ + k],
                         *(const float4*)&u[(size_t)mrow*CTX_ + k + 4]);
      short8 afr = pack8(*(const float4*)&gWf[(size_t)l15*GIN_ + k],
                         *(const float4*)&gWf[(size_t)l15*GIN_ + k + 4]);
      ga = __builtin_amdgcn_mfma_f32_16x16x32_bf16(afr, bfr, ga, 0,0,0);
    }
    #pragma unroll
    for (int t = 0; t < 16; ++t){                // x segment k=256..767
      const int k = t*32 + hi2*8;
      short8 bfr = *(const short8*)&xb[(size_t)mrow*IN_ + k];
      short8 afr = pack8(*(const float4*)&gWf[(size_t)l15*GIN_ + 256 + k],
                         *(const float4*)&gWf[(size_t)l15*GIN_ + 256 + k + 4]);
      ga = __builtin_amdgcn_mfma_f32_16x16x32_bf16(afr, bfr, ga, 0,0,0);
    }
    {                                            // d segment k=768..783, zero-padded
      short8 afr = {0,0,0,0,0,0,0,0}, bfr = {0,0,0,0,0,0,0,0};
      if (hi2 < 2){
        bfr = pack8(*(const float4*)&dd[(size_t)mrow*DEMO_ + hi2*8],
                    *(const float4*)&dd[(size_t)mrow*DEMO_ + hi2*8 + 4]);
        afr = pack8(*(const float4*)&gWf[(size_t)l15*GIN_ + 768 + hi2*8],
                    *(const float4*)&gWf[(size_t)l15*GIN_ + 768 + hi2*8 + 4]);
      }
      ga = __builtin_amdgcn_mfma_f32_16x16x32_bf16(afr, bfr, ga, 0,0,0);
    }
    // lane holds logits for m = l15 (col), e = hi2*4+r (row); softmax over e
    float v[4];
    #pragma unroll
    for (int r = 0; r < 4; ++r) v[r] = ga[r] + gbf[hi2*4 + r];
    float mx = fmaxf(fmaxf(v[0],v[1]), fmaxf(v[2],v[3]));
    mx = fmaxf(mx, __shfl_xor(mx, 16));
    mx = fmaxf(mx, __shfl_xor(mx, 32));
    float p[4], ssum = 0.f;
    #pragma unroll
    for (int r = 0; r < 4; ++r){ p[r] = __expf(v[r]-mx); ssum += p[r]; }
    ssum += __shfl_xor(ssum, 16);
    ssum += __shfl_xor(ssum, 32);
    const float inv = 1.f / ssum;
    #pragma unroll
    for (int r = 0; r < 4; ++r) sg[(wv*16 + l15)*17 + hi2*4 + r] = p[r]*inv;
  }
  __syncthreads();

  // ======== prologue: seed oacc with sum_e w[m,e]*b2[e,o] (every wave, own tile) ========
  floatx4 oacc[4][2];     // [mt over 64m][ot over 32o]
  #pragma unroll
  for (int mt = 0; mt < 4; ++mt)
    #pragma unroll
    for (int ot = 0; ot < 2; ++ot) oacc[mt][ot] = floatx4{0.f,0.f,0.f,0.f};
  #pragma unroll 1
  for (int e = 0; e < E_; ++e){
    float b2v[2];
    #pragma unroll
    for (int ot = 0; ot < 2; ++ot) b2v[ot] = b2g[e*OUT_ + s*32 + ot*16 + l15];
    #pragma unroll
    for (int mt = 0; mt < 4; ++mt)
      #pragma unroll
      for (int r = 0; r < 4; ++r){
        const float wg = sg[(m_g*64 + mt*16 + hi2*4 + r)*17 + e];
        #pragma unroll
        for (int ot = 0; ot < 2; ++ot) oacc[mt][ot][r] += wg * b2v[ot];
      }
  }

  // ======== expert loop ========
  #pragma unroll 1
  for (int e = 0; e < E_; ++e){
    // gate weights for this wave's GEMM2-A rows (m = m_g*64 + mt*16 + l15)
    float w_my[4];
    #pragma unroll
    for (int mt = 0; mt < 4; ++mt)
      w_my[mt] = sg[(m_g*64 + mt*16 + l15)*17 + e];

    // ---- GEMM1: C[h][m] = W1_e[s-quarter] @ x^T, b1 folded into C-init ----
    floatx4 g1[4][4];   // [ht over 64h][mt over 64m]
    #pragma unroll
    for (int ht = 0; ht < 4; ++ht){
      const float4 bv = *(const float4*)&b1g[e*HID_ + s*64 + ht*16 + hi2*4];
      #pragma unroll
      for (int mt = 0; mt < 4; ++mt) g1[ht][mt] = floatx4{bv.x, bv.y, bv.z, bv.w};
    }
    #pragma unroll 1
    for (int kc = 0; kc < 8; ++kc){
      stage_rows64<128>(s_x,  xb  + (size_t)blk_m0*IN_ + kc*64, IN_, tid);
      stage_rows64<256>(s_w1, w1b + (size_t)e*HID_*IN_ + kc*64, IN_, tid);
      __syncthreads();
      #pragma unroll
      for (int ks = 0; ks < 2; ++ks){
        const int sw = ((ks*4 + hi2) ^ (l15 & 7)) << 3;
        short8 af[4], bf[4];
        #pragma unroll
        for (int ht = 0; ht < 4; ++ht)
          af[ht] = *(const short8*)&s_w1[(s*64 + ht*16 + l15)*64 + sw];
        #pragma unroll
        for (int mt = 0; mt < 4; ++mt)
          bf[mt] = *(const short8*)&s_x[(m_g*64 + mt*16 + l15)*64 + sw];
        #pragma unroll
        for (int ht = 0; ht < 4; ++ht)
          #pragma unroll
          for (int mt = 0; mt < 4; ++mt)
            g1[ht][mt] = __builtin_amdgcn_mfma_f32_16x16x32_bf16(af[ht], bf[mt], g1[ht][mt], 0,0,0);
      }
      __syncthreads();
    }

    // ---- epilogue in-register: relu * gate -> bf16, k-permuted A-frags ----
    // a2[ks2][mt] position (hi2,j) holds h_local = ks2*32 + 16*(j>=4) + hi2*4 + (j&3)
    short8 a2[2][4];
    #pragma unroll
    for (int mt = 0; mt < 4; ++mt){
      const float wg = w_my[mt];
      short pk[16];
      #pragma unroll
      for (int ht = 0; ht < 4; ++ht)
        #pragma unroll
        for (int r = 0; r < 4; ++r)
          pk[ht*4 + r] = f2bf(fmaxf(g1[ht][mt][r], 0.f) * wg);
      #pragma unroll
      for (int ks2 = 0; ks2 < 2; ++ks2)
        #pragma unroll
        for (int j = 0; j < 8; ++j)
          a2[ks2][mt][j] = pk[ks2*8 + j];
    }

    // ---- GEMM2: 4 rounds over h-quarters; A own-quarter in-reg, rest via LDS ----
    #pragma unroll 1
    for (int hh = 0; hh < 4; ++hh){
      // stage W2 quarter [128o][64h] (issue loads first for latency)
      stage_rows64<128>(s_w2, w2b + (size_t)e*OUT_*HID_ + hh*64, HID_, tid);
      // own-quarter waves publish their H slice (4-short-block XOR swizzle by m&15)
      if (s == hh){
        #pragma unroll
        for (int ks2 = 0; ks2 < 2; ++ks2)
          #pragma unroll
          for (int mt = 0; mt < 4; ++mt){
            const int m = m_g*64 + mt*16 + l15;
            const int hb4a = ks2*8 + hi2;
            short4 lo, hi;
            lo.x=a2[ks2][mt][0]; lo.y=a2[ks2][mt][1]; lo.z=a2[ks2][mt][2]; lo.w=a2[ks2][mt][3];
            hi.x=a2[ks2][mt][4]; hi.y=a2[ks2][mt][5]; hi.z=a2[ks2][mt][6]; hi.w=a2[ks2][mt][7];
            *(short4*)&s_h[m*64 + ((hb4a     ^ (m & 15)) << 2)] = lo;
            *(short4*)&s_h[m*64 + (((hb4a+4) ^ (m & 15)) << 2)] = hi;
          }
      }
      __syncthreads();
      // A-frags (perm order)
      short8 A[2][4];
      if (s == hh){
        #pragma unroll
        for (int ks2 = 0; ks2 < 2; ++ks2)
          #pragma unroll
          for (int mt = 0; mt < 4; ++mt) A[ks2][mt] = a2[ks2][mt];
      } else {
        #pragma unroll
        for (int ks2 = 0; ks2 < 2; ++ks2)
          #pragma unroll
          for (int mt = 0; mt < 4; ++mt){
            const int m = m_g*64 + mt*16 + l15;
            const int hb4a = ks2*8 + hi2;
            const short4 lo = *(const short4*)&s_h[m*64 + ((hb4a     ^ (m & 15)) << 2)];
            const short4 hi = *(const short4*)&s_h[m*64 + (((hb4a+4) ^ (m & 15)) << 2)];
            short8 t;
            t[0]=lo.x; t[1]=lo.y; t[2]=lo.z; t[3]=lo.w;
            t[4]=hi.x; t[5]=hi.y; t[6]=hi.z; t[7]=hi.w;
            A[ks2][mt] = t;
          }
      }
      // B-frags (same perm order) from s_w2 (16B-block XOR swizzle by o&7)
      short8 Bf[2][2];
      #pragma unroll
      for (int ks2 = 0; ks2 < 2; ++ks2)
        #pragma unroll
        for (int ot = 0; ot < 2; ++ot){
          const int o = s*32 + ot*16 + l15;
          const int hb4a = ks2*8 + hi2, hb4b = hb4a + 4;
          const int pa = ((hb4a >> 1) ^ (o & 7));
          const int pb = ((hb4b >> 1) ^ (o & 7));
          const short4 lo = *(const short4*)&s_w2[o*64 + pa*8 + (hb4a & 1)*4];
          const short4 hi = *(const short4*)&s_w2[o*64 + pb*8 + (hb4b & 1)*4];
          short8 t;
          t[0]=lo.x; t[1]=lo.y; t[2]=lo.z; t[3]=lo.w;
          t[4]=hi.x; t[5]=hi.y; t[6]=hi.z; t[7]=hi.w;
          Bf[ks2][ot] = t;
        }
      #pragma unroll
      for (int ks2 = 0; ks2 < 2; ++ks2)
        #pragma unroll
        for (int mt = 0; mt < 4; ++mt)
          #pragma unroll
          for (int ot = 0; ot < 2; ++ot)
            oacc[mt][ot] = __builtin_amdgcn_mfma_f32_16x16x32_bf16(A[ks2][mt], Bf[ks2][ot], oacc[mt][ot], 0,0,0);
      __syncthreads();   // s_h/s_w2 consumed before next round/expert overwrites
    }
  }

  // ======== epilogue: direct stores (no atomics) ========
  #pragma unroll
  for (int mt = 0; mt < 4; ++mt)
    #pragma unroll
    for (int ot = 0; ot < 2; ++ot)
      #pragma unroll
      for (int r = 0; r < 4; ++r)
        out[(size_t)(blk_m0 + m_g*64 + mt*16 + hi2*4 + r)*OUT_ + s*32 + ot*16 + l15] = oacc[mt][ot][r];
}

extern "C" void kernel_launch(void* const* d_in, const int* in_sizes, int n_in,
                              void* d_out, int out_size, void* d_ws, size_t ws_size,
                              hipStream_t stream){
  const float* x  = (const float*)d_in[0];
  const float* u  = (const float*)d_in[1];
  const float* dd = (const float*)d_in[2];
  const float* gW = (const float*)d_in[3];
  const float* gb = (const float*)d_in[4];
  const float* W1 = (const float*)d_in[5];
  const float* b1 = (const float*)d_in[6];
  const float* W2 = (const float*)d_in[7];
  const float* b2 = (const float*)d_in[8];
  float* out = (float*)d_out;

  short* xb  = (short*)d_ws;
  short* w1b = xb  + (size_t)B_*IN_;
  short* w2b = w1b + (size_t)E_*HID_*IN_;

  hipLaunchKernelGGL(convert_kernel, dim3(4096), dim3(256), 0, stream, x, W1, W2, xb, w1b, w2b);
  hipLaunchKernelGGL(moe_kernel, dim3(B_/128), dim3(512), 0, stream,
                     xb, w1b, w2b, u, dd, gW, gb, b1, b2, out);
  (void)in_sizes; (void)n_in; (void)out_size; (void)ws_size;
}